// Round 5
// baseline (255.226 us; speedup 1.0000x reference)
//
#include <hip/hip_runtime.h>
#include <hip/hip_fp16.h>

// SimpleAttention on MI355X (gfx950), f16 MFMA path with fp32 accum.
// Pipeline: cast(x,wqkv,wout) -> QKV GEMM -> causal flash attn -> out GEMM.
// Q is pre-scaled by 0.125*log2(e) so attn softmax runs in exp2 domain.

typedef _Float16 half8 __attribute__((ext_vector_type(8)));
typedef _Float16 half4 __attribute__((ext_vector_type(4)));
typedef float f32x4 __attribute__((ext_vector_type(4)));

typedef const __attribute__((address_space(1))) void gvoid_t;
typedef __attribute__((address_space(3))) void lvoid_t;

#define LOG2E 1.4426950408889634f
#define QSCALE (0.125f * LOG2E)

// ---------------- fused fp32 -> fp16 cast, 8 elems/thread ----------------
// segments: x 524288 half8s, w_qkv 393216, w_out 131072  (total 1048576)
__global__ void cast_all_f16(const float* __restrict__ x, const float* __restrict__ wq,
                             const float* __restrict__ wo, _Float16* __restrict__ xh,
                             _Float16* __restrict__ wqh, _Float16* __restrict__ woh) {
  int i = blockIdx.x * blockDim.x + threadIdx.x;
  const float* src;
  _Float16* dst;
  int off;
  if (i < 524288) { src = x; dst = xh; off = i; }
  else if (i < 917504) { src = wq; dst = wqh; off = i - 524288; }
  else { src = wo; dst = woh; off = i - 917504; }
  const float4* p = reinterpret_cast<const float4*>(src) + (size_t)off * 2;
  float4 a = p[0], b = p[1];
  half8 h;
  h[0] = (_Float16)a.x; h[1] = (_Float16)a.y; h[2] = (_Float16)a.z; h[3] = (_Float16)a.w;
  h[4] = (_Float16)b.x; h[5] = (_Float16)b.y; h[6] = (_Float16)b.z; h[7] = (_Float16)b.w;
  reinterpret_cast<half8*>(dst)[off] = h;
}

// ---------------- GEMM: C[M,N] = A[M,K] * B[N,K]^T, K=1024 ----------------
// 128x128 tile, BK=32, 4 waves (each 64x64 = 4x4 frags of 16x16x32 f16 MFMA).
// EPI=0: scatter into Q[b,h,s,d] (pre-scaled), K[b,h,s,d], Vt[b,h,d,s] (f16)
// EPI=1: plain fp32 store to Co[M,1024]
template <int EPI>
__global__ __launch_bounds__(256) void gemm_f16(
    const _Float16* __restrict__ A, const _Float16* __restrict__ B,
    _Float16* __restrict__ Qo, _Float16* __restrict__ Ko, _Float16* __restrict__ Vto,
    float* __restrict__ Co)
{
  __shared__ __align__(16) _Float16 As[128 * 32];
  __shared__ __align__(16) _Float16 Bs[128 * 32];
  const int tid = threadIdx.x;
  const int lane = tid & 63;
  const int w = tid >> 6;
  const int lr = lane & 15, hi = lane >> 4;
  const int wr = w >> 1, wc = w & 1;
  const int gm = blockIdx.y, gn = blockIdx.x;
  const _Float16* gA = A + (size_t)gm * 128 * 1024;
  const _Float16* gB = B + (size_t)gn * 128 * 1024;
  f32x4 acc[4][4] = {};

#define STAGE(gp, sp)                                                                   \
  { _Pragma("unroll") for (int i_ = 0; i_ < 2; ++i_) {                                  \
      int c_ = i_ * 256 + tid; int r_ = c_ >> 2; int ko_ = (c_ & 3) * 8;                \
      __builtin_amdgcn_global_load_lds((gvoid_t*)((gp) + r_ * 1024 + ko_),              \
                                       (lvoid_t*)((sp) + c_ * 8), 16, 0, 0);            \
    } }

  STAGE(gA, As)
  STAGE(gB, Bs)
  for (int ks = 0;; ++ks) {
    __syncthreads();  // drains vmcnt: staged tile visible
    half8 af[4], bf[4];
#pragma unroll
    for (int mi = 0; mi < 4; ++mi)
      af[mi] = *reinterpret_cast<const half8*>(As + (wr * 64 + mi * 16 + lr) * 32 + hi * 8);
#pragma unroll
    for (int ni = 0; ni < 4; ++ni)
      bf[ni] = *reinterpret_cast<const half8*>(Bs + (wc * 64 + ni * 16 + lr) * 32 + hi * 8);
#pragma unroll
    for (int mi = 0; mi < 4; ++mi)
#pragma unroll
      for (int ni = 0; ni < 4; ++ni)
        acc[mi][ni] = __builtin_amdgcn_mfma_f32_16x16x32_f16(af[mi], bf[ni], acc[mi][ni], 0, 0, 0);
    if (ks == 31) break;
    __syncthreads();  // all waves done reading LDS
    STAGE(gA + (ks + 1) * 32, As)
    STAGE(gB + (ks + 1) * 32, Bs)
  }
#undef STAGE

  const int row0 = gm * 128 + wr * 64;
  const int col0 = gn * 128 + wc * 64;
  if (EPI == 0) {
#pragma unroll
    for (int ni = 0; ni < 4; ++ni) {
      int col = col0 + ni * 16 + lr;          // 0..3071
      int t = col >> 10, h = (col >> 6) & 15, d = col & 63;
#pragma unroll
      for (int mi = 0; mi < 4; ++mi) {
        int row = row0 + mi * 16 + hi * 4;    // j=0 row; j stays within same b (row%4==0)
        int b = row >> 11, s = row & 2047;
        if (t == 2) {
          // Vt[b,h,d,s]: 4 j-values are consecutive in s -> one 8B store
          half4 pk = { (_Float16)acc[mi][ni][0], (_Float16)acc[mi][ni][1],
                       (_Float16)acc[mi][ni][2], (_Float16)acc[mi][ni][3] };
          *reinterpret_cast<half4*>(Vto + ((size_t)(b * 16 + h) * 64 + d) * 2048 + s) = pk;
        } else if (t == 0) {
#pragma unroll
          for (int j = 0; j < 4; ++j)
            Qo[(size_t)((b * 16 + h) * 2048 + s + j) * 64 + d] =
                (_Float16)(acc[mi][ni][j] * QSCALE);
        } else {
#pragma unroll
          for (int j = 0; j < 4; ++j)
            Ko[(size_t)((b * 16 + h) * 2048 + s + j) * 64 + d] = (_Float16)acc[mi][ni][j];
        }
      }
    }
  } else {
#pragma unroll
    for (int mi = 0; mi < 4; ++mi)
#pragma unroll
      for (int j = 0; j < 4; ++j) {
        int row = row0 + mi * 16 + hi * 4 + j;
#pragma unroll
        for (int ni = 0; ni < 4; ++ni) {
          int col = col0 + ni * 16 + lr;
          Co[(size_t)row * 1024 + col] = acc[mi][ni][j];
        }
      }
  }
}

// ---------------- causal flash attention ----------------
// grid (16, 32): x = q-tile (descending work order), y = b*NH+h.
// 4 waves/block, each owns 32 q-rows; 64-key tiles; online softmax (exp2 domain).
// No barriers in the k-loop (per-wave P buffer) -> per-wave trip count:
// wave stops after its own diagonal tile, nkt = (qg0>>6)+1.
// K and V fragments are loaded together at tile top so global latency hides
// under the softmax VALU phase (T14-lite).
// __launch_bounds__(256,2): pin VGPR<=256 so occupancy stays 2 waves/SIMD.
__global__ __launch_bounds__(256, 2) void attn_f16(
    const _Float16* __restrict__ Qg, const _Float16* __restrict__ Kg,
    const _Float16* __restrict__ Vtg, _Float16* __restrict__ AO)
{
  const int bh = blockIdx.y;
  const int qt = 15 - blockIdx.x;  // big tiles launch first
  const int tid = threadIdx.x;
  const int w = tid >> 6, lane = tid & 63;
  const int lr = lane & 15, hi = lane >> 4;
  const _Float16* Qh = Qg + (size_t)bh * 2048 * 64;
  const _Float16* Kh = Kg + (size_t)bh * 2048 * 64;
  const _Float16* Vh = Vtg + (size_t)bh * 64 * 2048;  // [d][s]
  const int qg0 = qt * 128 + w * 32;
  __shared__ __align__(16) _Float16 Plds[4][32][88];  // stride 88: 16B-aligned rows, conflict-light
  _Float16(*P)[88] = Plds[w];

  // Q fragments hoisted to registers: 32 rows x 64 d per wave (pre-scaled by QSCALE)
  half8 qf[2][2];
#pragma unroll
  for (int mi = 0; mi < 2; ++mi)
#pragma unroll
    for (int kk = 0; kk < 2; ++kk)
      qf[mi][kk] = *reinterpret_cast<const half8*>(
          Qh + (size_t)(qg0 + mi * 16 + lr) * 64 + kk * 32 + hi * 8);

  f32x4 accO[2][4] = {};
  f32x4 mrun[2], lrun[2];
#pragma unroll
  for (int mi = 0; mi < 2; ++mi)
#pragma unroll
    for (int j = 0; j < 4; ++j) { mrun[mi][j] = -1e30f; lrun[mi][j] = 0.f; }

  const int nkt = (qg0 >> 6) + 1;  // last tile containing key <= max own row
  for (int kt = 0; kt < nkt; ++kt) {
    const int k0 = kt * 64;
    const bool diag = (k0 + 63 > qg0);  // tile contains keys beyond some own row
    // ---- all global loads for this tile issue together (K frags + V frags) ----
    half8 kf[4][2];
#pragma unroll
    for (int ni = 0; ni < 4; ++ni)
#pragma unroll
      for (int kk = 0; kk < 2; ++kk)
        kf[ni][kk] = *reinterpret_cast<const half8*>(
            Kh + (size_t)(k0 + ni * 16 + lr) * 64 + kk * 32 + hi * 8);
    half8 vf[2][4];
#pragma unroll
    for (int kk = 0; kk < 2; ++kk)
#pragma unroll
      for (int nd = 0; nd < 4; ++nd)
        vf[kk][nd] = *reinterpret_cast<const half8*>(
            Vh + (size_t)(nd * 16 + lr) * 2048 + k0 + kk * 32 + hi * 8);
    // ---- scores2 = (Q*QSCALE) K^T  (log2-domain scores) ----
    f32x4 accS[2][4] = {};
#pragma unroll
    for (int mi = 0; mi < 2; ++mi)
#pragma unroll
      for (int ni = 0; ni < 4; ++ni)
#pragma unroll
        for (int kk = 0; kk < 2; ++kk)
          accS[mi][ni] = __builtin_amdgcn_mfma_f32_16x16x32_f16(qf[mi][kk], kf[ni][kk], accS[mi][ni], 0, 0, 0);
    // ---- causal mask (scale already folded into Q) ----
    if (diag) {
#pragma unroll
      for (int mi = 0; mi < 2; ++mi)
#pragma unroll
        for (int ni = 0; ni < 4; ++ni)
#pragma unroll
          for (int j = 0; j < 4; ++j) {
            int colg = k0 + ni * 16 + lr;
            int rowg = qg0 + mi * 16 + hi * 4 + j;
            if (colg > rowg) accS[mi][ni][j] = -1e30f;
          }
    }
    // ---- online softmax, exp2 domain (all 64 lanes; 16-lane xor reductions) ----
#pragma unroll
    for (int mi = 0; mi < 2; ++mi) {
      f32x4 rmax = accS[mi][0];
#pragma unroll
      for (int ni = 1; ni < 4; ++ni)
#pragma unroll
        for (int j = 0; j < 4; ++j) rmax[j] = fmaxf(rmax[j], accS[mi][ni][j]);
#pragma unroll
      for (int d = 1; d < 16; d <<= 1)
#pragma unroll
        for (int j = 0; j < 4; ++j) rmax[j] = fmaxf(rmax[j], __shfl_xor(rmax[j], d));
      f32x4 mnew, corr;
#pragma unroll
      for (int j = 0; j < 4; ++j) {
        mnew[j] = fmaxf(mrun[mi][j], rmax[j]);
        corr[j] = exp2f(mrun[mi][j] - mnew[j]);
        mrun[mi][j] = mnew[j];
      }
      f32x4 rsum = {};
#pragma unroll
      for (int ni = 0; ni < 4; ++ni)
#pragma unroll
        for (int j = 0; j < 4; ++j) {
          float pv = exp2f(accS[mi][ni][j] - mnew[j]);
          rsum[j] += pv;
          P[mi * 16 + hi * 4 + j][ni * 16 + lr] = (_Float16)pv;  // C-layout -> LDS
        }
#pragma unroll
      for (int d = 1; d < 16; d <<= 1)
#pragma unroll
        for (int j = 0; j < 4; ++j) rsum[j] += __shfl_xor(rsum[j], d);
#pragma unroll
      for (int j = 0; j < 4; ++j) lrun[mi][j] = lrun[mi][j] * corr[j] + rsum[j];
#pragma unroll
      for (int nd = 0; nd < 4; ++nd)
#pragma unroll
        for (int j = 0; j < 4; ++j) accO[mi][nd][j] *= corr[j];
    }
    // ---- PV: O += P @ V (P re-read in A-frag layout; V already in registers) ----
#pragma unroll
    for (int mi = 0; mi < 2; ++mi)
#pragma unroll
      for (int kk = 0; kk < 2; ++kk) {
        half8 pa = *reinterpret_cast<const half8*>(&P[mi * 16 + lr][kk * 32 + hi * 8]);
#pragma unroll
        for (int nd = 0; nd < 4; ++nd)
          accO[mi][nd] = __builtin_amdgcn_mfma_f32_16x16x32_f16(pa, vf[kk][nd], accO[mi][nd], 0, 0, 0);
      }
  }
  // ---- epilogue: AO[b, s, h*64+d] = O / l ----
  const int b = bh >> 4, h = bh & 15;
#pragma unroll
  for (int mi = 0; mi < 2; ++mi) {
    f32x4 inv;
#pragma unroll
    for (int j = 0; j < 4; ++j) inv[j] = 1.0f / lrun[mi][j];
#pragma unroll
    for (int nd = 0; nd < 4; ++nd)
#pragma unroll
      for (int j = 0; j < 4; ++j) {
        int s = qg0 + mi * 16 + hi * 4 + j;
        int d = nd * 16 + lr;
        AO[(size_t)(b * 2048 + s) * 1024 + h * 64 + d] = (_Float16)(accO[mi][nd][j] * inv[j]);
      }
  }
}

extern "C" void kernel_launch(void* const* d_in, const int* in_sizes, int n_in,
                              void* d_out, int out_size, void* d_ws, size_t ws_size,
                              hipStream_t stream) {
  const float* x = (const float*)d_in[0];      // [2,2048,1024]
  const float* wqkv = (const float*)d_in[1];   // [3072,1024]
  const float* wout = (const float*)d_in[2];   // [1024,1024]
  float* out = (float*)d_out;                  // [2,2048,1024] fp32
  char* ws = (char*)d_ws;
  // workspace map (48 MB total)
  _Float16* xh  = (_Float16*)(ws + (size_t)0);          // 8 MB
  _Float16* wqh = (_Float16*)(ws + ((size_t)8 << 20));  // 6 MB
  _Float16* woh = (_Float16*)(ws + ((size_t)14 << 20)); // 2 MB
  _Float16* Qb  = (_Float16*)(ws + ((size_t)16 << 20)); // 8 MB [b,h,s,d] pre-scaled
  _Float16* Kb  = (_Float16*)(ws + ((size_t)24 << 20)); // 8 MB [b,h,s,d]
  _Float16* Vtb = (_Float16*)(ws + ((size_t)32 << 20)); // 8 MB [b,h,d,s]
  _Float16* AOb = (_Float16*)(ws + ((size_t)40 << 20)); // 8 MB [b,s,h*64+d]

  cast_all_f16<<<dim3(4096), 256, 0, stream>>>(x, wqkv, wout, xh, wqh, woh);
  gemm_f16<0><<<dim3(24, 32), 256, 0, stream>>>(xh, wqh, Qb, Kb, Vtb, nullptr);
  attn_f16<<<dim3(16, 32), 256, 0, stream>>>(Qb, Kb, Vtb, AOb);
  gemm_f16<1><<<dim3(8, 32), 256, 0, stream>>>(AOb, woh, nullptr, nullptr, nullptr, out);
}